// Round 11
// baseline (250.219 us; speedup 1.0000x reference)
//
#include <hip/hip_runtime.h>
#include <hip/hip_bf16.h>

#define NROWS 16384   // B*S
#define KD    2048    // D
#define NE    16      // experts
#define ROWS_PER_BLK 64
#define KQ    1024    // K-range per K-group (2 groups)
#define TKG   64      // K-floats staged per group per step
#define NSTEP (KQ / TKG)   // 16

// v11: R=2 rows/lane, 2-way K-split, sized to fit the observed 128-VGPR cap.
//  - block = 512 thr / 8 waves; wave w -> (row-quarter q=w&3, K-group g=w>>2)
//  - lane = (rgrp=lane>>3 -> 2 rows, seg=lane&7 -> 8-float K-slice per step)
//  - regs: acc 64 + x dbuf 32 + ptrs ~25 = ~120 <= 128 (no spill by design)
//  - LDS 32 KB -> 2 blocks/CU -> 4 waves/SIMD latency hiding
// Output FLOAT32: [262144 probs][32768 ids-as-floats].

__device__ __forceinline__ void gload_lds16(const float* g, float* l) {
    __builtin_amdgcn_global_load_lds(
        (const __attribute__((address_space(1))) void*)g,
        (__attribute__((address_space(3))) void*)l,
        16, 0, 0);
}

__global__ __launch_bounds__(512)
void noisy_router_kernel(const float* __restrict__ x,
                         const float* __restrict__ noise,
                         const float* __restrict__ Wfc,
                         const float* __restrict__ bfc,
                         const float* __restrict__ Wns,
                         const float* __restrict__ bns,
                         float* __restrict__ out)
{
    __shared__ float lds[8192];    // 32 KB: wt[2 groups][2 bufs][32*64]; epilogue reuse

    const int tid  = threadIdx.x;
    const int lane = tid & 63;
    const int w    = tid >> 6;     // 0..7
    const int g    = w >> 2;       // K-group 0..1
    const int q    = w & 3;        // row-quarter 0..3
    const int seg  = lane & 7;
    const int rgrp = lane >> 3;

    const int rowbase = blockIdx.x * ROWS_PER_BLK + q * 16 + rgrp * 2;
    const int kbase   = g * KQ;

    float* const wt0 = lds + (g * 2 + 0) * 2048;
    float* const wt1 = lds + (g * 2 + 1) * 2048;

    // staging map: group's 4 waves form vt=0..255; instr 0 -> Wfc rows 0..15,
    // instr 1 -> Wns rows (LDS rows 16..31); col = (vt&15)*4.
    // Per wave: 4 consecutive rows, byte range linear in lane (base + lane*16).
    const int vt    = q * 64 + lane;
    const int wrow0 = vt >> 4;            // 0..15
    const int scol  = (vt & 15) * 4;
    const float* wsrcA = Wfc + (size_t)wrow0 * KD + kbase + scol;
    const float* wsrcB = Wns + (size_t)wrow0 * KD + kbase + scol;
    const int sdst0 = wrow0 * 64 + scol;
    const int sdst1 = (wrow0 + 16) * 64 + scol;

    const float* xb0 = x + (size_t)rowbase * KD + kbase + seg * 8;
    const float* xb1 = xb0 + KD;

    float accA[2][16], accB[2][16];
    #pragma unroll
    for (int j = 0; j < 2; ++j)
        #pragma unroll
        for (int e = 0; e < NE; ++e) { accA[j][e] = 0.f; accB[j][e] = 0.f; }

    float4 xA[2][2], xB[2][2];    // two named x buffers; all indices static

#define STAGE(DST, S)                                                   \
    { gload_lds16(wsrcA + (S) * TKG, (DST) + sdst0);                    \
      gload_lds16(wsrcB + (S) * TKG, (DST) + sdst1); }

#define XLOAD(XV, S)                                                    \
    { XV[0][0] = *(const float4*)(xb0 + (S) * TKG);                     \
      XV[0][1] = *(const float4*)(xb0 + (S) * TKG + 4);                 \
      XV[1][0] = *(const float4*)(xb1 + (S) * TKG);                     \
      XV[1][1] = *(const float4*)(xb1 + (S) * TKG + 4); }

#define COMPUTE(WT, XV)                                                 \
    { const float* wp = (WT) + seg * 8;                                 \
      _Pragma("unroll")                                                 \
      for (int e = 0; e < NE; ++e) {                                    \
          const float4 a0 = *(const float4*)(wp + e * 64);              \
          const float4 a1 = *(const float4*)(wp + e * 64 + 4);          \
          const float4 b0 = *(const float4*)(wp + (16 + e) * 64);       \
          const float4 b1 = *(const float4*)(wp + (16 + e) * 64 + 4);   \
          _Pragma("unroll")                                             \
          for (int j = 0; j < 2; ++j) {                                 \
              const float4 x0 = XV[j][0], x1 = XV[j][1];                \
              float sA = accA[j][e], sB = accB[j][e];                   \
              sA = fmaf(x0.x, a0.x, sA); sA = fmaf(x0.y, a0.y, sA);     \
              sA = fmaf(x0.z, a0.z, sA); sA = fmaf(x0.w, a0.w, sA);     \
              sA = fmaf(x1.x, a1.x, sA); sA = fmaf(x1.y, a1.y, sA);     \
              sA = fmaf(x1.z, a1.z, sA); sA = fmaf(x1.w, a1.w, sA);     \
              sB = fmaf(x0.x, b0.x, sB); sB = fmaf(x0.y, b0.y, sB);     \
              sB = fmaf(x0.z, b0.z, sB); sB = fmaf(x0.w, b0.w, sB);     \
              sB = fmaf(x1.x, b1.x, sB); sB = fmaf(x1.y, b1.y, sB);     \
              sB = fmaf(x1.z, b1.z, sB); sB = fmaf(x1.w, b1.w, sB);     \
              accA[j][e] = sA; accB[j][e] = sB;                         \
          }                                                             \
      } }

    // prologue
    STAGE(wt0, 0);
    XLOAD(xA, 0);

    #pragma unroll 1
    for (int sp = 0; sp < NSTEP; sp += 2) {
        __syncthreads();                 // tile sp + x(sp) ready (vmcnt drained)
        STAGE(wt1, sp + 1);
        XLOAD(xB, sp + 1);
        COMPUTE(wt0, xA);
        __syncthreads();                 // tile sp+1 ready
        if (sp + 2 < NSTEP) {
            STAGE(wt0, sp + 2);
            XLOAD(xA, sp + 2);
        }
        COMPUTE(wt1, xB);
    }
#undef STAGE
#undef XLOAD
#undef COMPUTE

    // ---- butterfly over the 8 k-segs (masks 1,2,4 stay within seg-group) ----
    #pragma unroll
    for (int j = 0; j < 2; ++j)
        #pragma unroll
        for (int e = 0; e < NE; ++e) {
            float a = accA[j][e], b = accB[j][e];
            a += __shfl_xor(a, 1); a += __shfl_xor(a, 2); a += __shfl_xor(a, 4);
            b += __shfl_xor(b, 1); b += __shfl_xor(b, 2); b += __shfl_xor(b, 4);
            accA[j][e] = a; accB[j][e] = b;
        }

    __syncthreads();                  // all tile reads done; lds reusable
    float* const slab = lds;          // [2 groups][64 rows][32 outs] = 4096 floats
    float* const red  = lds + 4096;   // [64 rows][stride 36]

    if (seg == 0) {
        #pragma unroll
        for (int j = 0; j < 2; ++j) {
            const int rl = q * 16 + rgrp * 2 + j;
            float* dst = slab + g * 2048 + rl * 32;
            #pragma unroll
            for (int qd = 0; qd < 4; ++qd) {
                *(float4*)(dst + qd * 4)      = *(float4*)&accA[j][qd * 4];
                *(float4*)(dst + 16 + qd * 4) = *(float4*)&accB[j][qd * 4];
            }
        }
    }
    __syncthreads();

    {   // combine the 2 group-partials
        const int row = tid >> 3, qd = tid & 7;
        float4 sum = make_float4(0.f, 0.f, 0.f, 0.f);
        #pragma unroll
        for (int gg = 0; gg < 2; ++gg) {
            const float4 v = *(const float4*)(slab + gg * 2048 + row * 32 + qd * 4);
            sum.x += v.x; sum.y += v.y; sum.z += v.z; sum.w += v.w;
        }
        *(float4*)(red + row * 36 + qd * 4) = sum;
    }
    __syncthreads();

    // ---- per-row epilogue: softplus noise, top-2, sparse softmax ----
    if (tid < ROWS_PER_BLK) {
        const int r = tid;
        float rv[32];
        #pragma unroll
        for (int qd = 0; qd < 8; ++qd)
            *(float4*)&rv[qd * 4] = *(const float4*)(red + r * 36 + qd * 4);

        const size_t grow = (size_t)blockIdx.x * ROWS_PER_BLK + r;
        const float* nzp = noise + grow * NE;

        float m1 = -1e30f, m2 = -1e30f;
        int i1 = 0, i2 = 0;
        #pragma unroll
        for (int j = 0; j < NE; ++j) {
            const float z  = rv[16 + j] + bns[j];
            const float sp = fmaxf(z, 0.f) + log1pf(expf(-fabsf(z)));  // jax softplus
            const float v  = fmaf(nzp[j], sp, rv[j] + bfc[j]);
            if (v > m1)      { m2 = m1; i2 = i1; m1 = v; i1 = j; }     // ties -> lower idx
            else if (v > m2) { m2 = v;  i2 = j; }
        }
        const float e2  = expf(m2 - m1);
        const float inv = 1.f / (1.f + e2);

        float* po = out + grow * NE;
        #pragma unroll
        for (int j = 0; j < NE; ++j) {
            po[j] = (j == i1) ? inv : ((j == i2) ? e2 * inv : 0.f);
        }
        float* pi = out + (size_t)NROWS * NE + grow * 2;
        pi[0] = (float)i1;
        pi[1] = (float)i2;
    }
}

extern "C" void kernel_launch(void* const* d_in, const int* in_sizes, int n_in,
                              void* d_out, int out_size, void* d_ws, size_t ws_size,
                              hipStream_t stream)
{
    const float* x     = (const float*)d_in[0];
    const float* noise = (const float*)d_in[1];
    const float* Wfc   = (const float*)d_in[2];
    const float* bfc   = (const float*)d_in[3];
    const float* Wns   = (const float*)d_in[4];
    const float* bns   = (const float*)d_in[5];
    float* out = (float*)d_out;

    noisy_router_kernel<<<NROWS / ROWS_PER_BLK, 512, 0, stream>>>(
        x, noise, Wfc, bfc, Wns, bns, out);
}

// Round 13
// 249.529 us; speedup vs baseline: 1.0028x; 1.0028x over previous
//
#include <hip/hip_runtime.h>
#include <hip/hip_bf16.h>

#define NROWS 16384   // B*S
#define KD    2048    // D
#define NE    16      // experts
#define ROWS_PER_BLK 64
#define KQ    1024    // K-range per K-group (2 groups)
#define TKG   64      // K-floats staged per group per step
#define NSTEP (KQ / TKG)   // 16

// v12 = v11 with the scratch-demotion fixed: NO address-of on thread-private
// arrays (slab writes are scalar stores; epilogue reads LDS directly).
// Evidence: rounds 8-11 all wrote ~550 MB scratch = acc_floats*4B*131072thr*NSTEP
// exactly; the float4-punned &accA[j][..] in the slab write blocked SROA.
//  - block = 512 thr / 8 waves; wave w -> (row-quarter q=w&3, K-group g=w>>2)
//  - lane = (rgrp=lane>>3 -> 2 rows, seg=lane&7 -> 8-float K-slice per step)
//  - W-stack tile [32][64] double-buffered in LDS via global_load_lds
//  - LDS 32 KB -> 2 blocks/CU -> 4 waves/SIMD latency hiding
// Output FLOAT32: [262144 probs][32768 ids-as-floats].

__device__ __forceinline__ void gload_lds16(const float* g, float* l) {
    __builtin_amdgcn_global_load_lds(
        (const __attribute__((address_space(1))) void*)g,
        (__attribute__((address_space(3))) void*)l,
        16, 0, 0);
}

__global__ __launch_bounds__(512)
void noisy_router_kernel(const float* __restrict__ x,
                         const float* __restrict__ noise,
                         const float* __restrict__ Wfc,
                         const float* __restrict__ bfc,
                         const float* __restrict__ Wns,
                         const float* __restrict__ bns,
                         float* __restrict__ out)
{
    __shared__ float lds[8192];    // 32 KB: wt[2 groups][2 bufs][32*64]; epilogue reuse

    const int tid  = threadIdx.x;
    const int lane = tid & 63;
    const int w    = tid >> 6;     // 0..7
    const int g    = w >> 2;       // K-group 0..1
    const int q    = w & 3;        // row-quarter 0..3
    const int seg  = lane & 7;
    const int rgrp = lane >> 3;

    const int rowbase = blockIdx.x * ROWS_PER_BLK + q * 16 + rgrp * 2;
    const int kbase   = g * KQ;

    float* const wt0 = lds + (g * 2 + 0) * 2048;
    float* const wt1 = lds + (g * 2 + 1) * 2048;

    // staging map: group's 4 waves form vt=0..255; instr 0 -> Wfc rows 0..15
    // (LDS rows 0..15), instr 1 -> Wns rows (LDS rows 16..31). Row stride
    // 64 floats = 256 B and 16 lanes/row x 16 B -> LDS dest = base + lane*16. 
    const int vt    = q * 64 + lane;
    const int wrow0 = vt >> 4;            // 0..15
    const int scol  = (vt & 15) * 4;
    const float* wsrcA = Wfc + (size_t)wrow0 * KD + kbase + scol;
    const float* wsrcB = Wns + (size_t)wrow0 * KD + kbase + scol;
    const int sdst0 = wrow0 * 64 + scol;
    const int sdst1 = (wrow0 + 16) * 64 + scol;

    const float* xb0 = x + (size_t)rowbase * KD + kbase + seg * 8;
    const float* xb1 = xb0 + KD;

    float accA[2][16], accB[2][16];
    #pragma unroll
    for (int j = 0; j < 2; ++j)
        #pragma unroll
        for (int e = 0; e < NE; ++e) { accA[j][e] = 0.f; accB[j][e] = 0.f; }

    float4 xA[2][2], xB[2][2];    // two named x buffers; all indices static

#define STAGE(DST, S)                                                   \
    { gload_lds16(wsrcA + (S) * TKG, (DST) + sdst0);                    \
      gload_lds16(wsrcB + (S) * TKG, (DST) + sdst1); }

#define XLOAD(XV, S)                                                    \
    { XV[0][0] = *(const float4*)(xb0 + (S) * TKG);                     \
      XV[0][1] = *(const float4*)(xb0 + (S) * TKG + 4);                 \
      XV[1][0] = *(const float4*)(xb1 + (S) * TKG);                     \
      XV[1][1] = *(const float4*)(xb1 + (S) * TKG + 4); }

#define COMPUTE(WT, XV)                                                 \
    { const float* wp = (WT) + seg * 8;                                 \
      _Pragma("unroll")                                                 \
      for (int e = 0; e < NE; ++e) {                                    \
          const float4 a0 = *(const float4*)(wp + e * 64);              \
          const float4 a1 = *(const float4*)(wp + e * 64 + 4);          \
          const float4 b0 = *(const float4*)(wp + (16 + e) * 64);       \
          const float4 b1 = *(const float4*)(wp + (16 + e) * 64 + 4);   \
          _Pragma("unroll")                                             \
          for (int j = 0; j < 2; ++j) {                                 \
              const float4 x0 = XV[j][0], x1 = XV[j][1];                \
              float sA = accA[j][e], sB = accB[j][e];                   \
              sA = fmaf(x0.x, a0.x, sA); sA = fmaf(x0.y, a0.y, sA);     \
              sA = fmaf(x0.z, a0.z, sA); sA = fmaf(x0.w, a0.w, sA);     \
              sA = fmaf(x1.x, a1.x, sA); sA = fmaf(x1.y, a1.y, sA);     \
              sA = fmaf(x1.z, a1.z, sA); sA = fmaf(x1.w, a1.w, sA);     \
              sB = fmaf(x0.x, b0.x, sB); sB = fmaf(x0.y, b0.y, sB);     \
              sB = fmaf(x0.z, b0.z, sB); sB = fmaf(x0.w, b0.w, sB);     \
              sB = fmaf(x1.x, b1.x, sB); sB = fmaf(x1.y, b1.y, sB);     \
              sB = fmaf(x1.z, b1.z, sB); sB = fmaf(x1.w, b1.w, sB);     \
              accA[j][e] = sA; accB[j][e] = sB;                         \
          }                                                             \
      } }

    // prologue
    STAGE(wt0, 0);
    XLOAD(xA, 0);

    #pragma unroll 1
    for (int sp = 0; sp < NSTEP; sp += 2) {
        __syncthreads();                 // tile sp + x(sp) ready (vmcnt drained)
        STAGE(wt1, sp + 1);
        XLOAD(xB, sp + 1);
        COMPUTE(wt0, xA);
        __syncthreads();                 // tile sp+1 ready
        if (sp + 2 < NSTEP) {
            STAGE(wt0, sp + 2);
            XLOAD(xA, sp + 2);
        }
        COMPUTE(wt1, xB);
    }
#undef STAGE
#undef XLOAD
#undef COMPUTE

    // ---- butterfly over the 8 k-segs (masks 1,2,4 stay within seg-group) ----
    #pragma unroll
    for (int j = 0; j < 2; ++j)
        #pragma unroll
        for (int e = 0; e < NE; ++e) {
            float a = accA[j][e], b = accB[j][e];
            a += __shfl_xor(a, 1); a += __shfl_xor(a, 2); a += __shfl_xor(a, 4);
            b += __shfl_xor(b, 1); b += __shfl_xor(b, 2); b += __shfl_xor(b, 4);
            accA[j][e] = a; accB[j][e] = b;
        }

    __syncthreads();                  // all tile reads done; lds reusable
    float* const slab = lds;          // [2 groups][64 rows][32 outs] = 4096 floats
    float* const red  = lds + 4096;   // [64 rows][stride 36]

    if (seg == 0) {
        #pragma unroll
        for (int j = 0; j < 2; ++j) {
            const int rl = q * 16 + rgrp * 2 + j;
            float* dst = slab + g * 2048 + rl * 32;
            #pragma unroll
            for (int qd = 0; qd < 16; ++qd) dst[qd] = accA[j][qd];       // scalar stores:
            #pragma unroll
            for (int qd = 0; qd < 16; ++qd) dst[16 + qd] = accB[j][qd];  // no &acc anywhere
        }
    }
    __syncthreads();

    {   // combine the 2 group-partials (float4 on LDS pointers only)
        const int row = tid >> 3, qd = tid & 7;
        float4 sum = make_float4(0.f, 0.f, 0.f, 0.f);
        #pragma unroll
        for (int gg = 0; gg < 2; ++gg) {
            const float4 v = *(const float4*)(slab + gg * 2048 + row * 32 + qd * 4);
            sum.x += v.x; sum.y += v.y; sum.z += v.z; sum.w += v.w;
        }
        *(float4*)(red + row * 36 + qd * 4) = sum;
    }
    __syncthreads();

    // ---- per-row epilogue: softplus noise, top-2, sparse softmax ----
    if (tid < ROWS_PER_BLK) {
        const int r = tid;
        const float* rowp = red + r * 36;   // read LDS directly, no private copy
        const size_t grow = (size_t)blockIdx.x * ROWS_PER_BLK + r;
        const float* nzp = noise + grow * NE;

        float m1 = -1e30f, m2 = -1e30f;
        int i1 = 0, i2 = 0;
        #pragma unroll
        for (int j = 0; j < NE; ++j) {
            const float z  = rowp[16 + j] + bns[j];
            const float sp = fmaxf(z, 0.f) + log1pf(expf(-fabsf(z)));  // jax softplus
            const float v  = fmaf(nzp[j], sp, rowp[j] + bfc[j]);
            if (v > m1)      { m2 = m1; i2 = i1; m1 = v; i1 = j; }     // ties -> lower idx
            else if (v > m2) { m2 = v;  i2 = j; }
        }
        const float e2  = expf(m2 - m1);
        const float inv = 1.f / (1.f + e2);

        float* po = out + grow * NE;
        #pragma unroll
        for (int j = 0; j < NE; ++j) {
            po[j] = (j == i1) ? inv : ((j == i2) ? e2 * inv : 0.f);
        }
        float* pi = out + (size_t)NROWS * NE + grow * 2;
        pi[0] = (float)i1;
        pi[1] = (float)i2;
    }
}

extern "C" void kernel_launch(void* const* d_in, const int* in_sizes, int n_in,
                              void* d_out, int out_size, void* d_ws, size_t ws_size,
                              hipStream_t stream)
{
    const float* x     = (const float*)d_in[0];
    const float* noise = (const float*)d_in[1];
    const float* Wfc   = (const float*)d_in[2];
    const float* bfc   = (const float*)d_in[3];
    const float* Wns   = (const float*)d_in[4];
    const float* bns   = (const float*)d_in[5];
    float* out = (float*)d_out;

    noisy_router_kernel<<<NROWS / ROWS_PER_BLK, 512, 0, stream>>>(
        x, noise, Wfc, bfc, Wns, bns, out);
}

// Round 14
// 242.982 us; speedup vs baseline: 1.0298x; 1.0269x over previous
//
#include <hip/hip_runtime.h>
#include <hip/hip_bf16.h>

#define NROWS 16384   // B*S
#define KD    2048    // D
#define NE    16      // experts
#define ROWS_PER_BLK 64
#define KQ    1024    // K-range per K-group (2 groups)
#define TKG   64      // K-floats staged per group per step
#define NSTEP (KQ / TKG)   // 16

// v14 = v11 geometry with ZERO thread-private arrays.
// Rounds 8-13 all wrote ~550-560 MB scratch (= full acc set re-stored per
// COMPUTE): array accumulators inside partially-unrolled pragma nests were
// demoted to allocas (rule #20). Here every accumulator and x value is an
// individually NAMED scalar via X-macros - no alloca can exist.
//  - block = 512 thr / 8 waves; wave w -> (row-quarter q=w&3, K-group g=w>>2)
//  - lane = (rgrp=lane>>3 -> 2 rows, seg=lane&7 -> 8-float K-slice per step)
//  - W-stack tile [32][64] double-buffered in LDS via global_load_lds
//  - LDS 32 KB -> 2+ blocks/CU
// Output FLOAT32: [262144 probs][32768 ids-as-floats].

__device__ __forceinline__ void gload_lds16(const float* g, float* l) {
    __builtin_amdgcn_global_load_lds(
        (const __attribute__((address_space(1))) void*)g,
        (__attribute__((address_space(3))) void*)l,
        16, 0, 0);
}

#define FOR_E1(F) F(0) F(1) F(2) F(3) F(4) F(5) F(6) F(7) \
                  F(8) F(9) F(10) F(11) F(12) F(13) F(14) F(15)
#define FOR_E2(F, A1, A2) \
    F(0,A1,A2) F(1,A1,A2) F(2,A1,A2) F(3,A1,A2) F(4,A1,A2) F(5,A1,A2) \
    F(6,A1,A2) F(7,A1,A2) F(8,A1,A2) F(9,A1,A2) F(10,A1,A2) F(11,A1,A2) \
    F(12,A1,A2) F(13,A1,A2) F(14,A1,A2) F(15,A1,A2)

#define DECL_ACC(e) float accA0_##e = 0.f, accA1_##e = 0.f, \
                          accB0_##e = 0.f, accB1_##e = 0.f;

#define FMA_ONE(e, WT, XS) { \
    const float4 a0 = *(const float4*)((WT) + wpo + (e) * 64);            \
    const float4 a1 = *(const float4*)((WT) + wpo + (e) * 64 + 4);        \
    const float4 b0 = *(const float4*)((WT) + wpo + (16 + (e)) * 64);     \
    const float4 b1 = *(const float4*)((WT) + wpo + (16 + (e)) * 64 + 4); \
    accA0_##e = fmaf(x0lo_##XS.x, a0.x, accA0_##e); \
    accA0_##e = fmaf(x0lo_##XS.y, a0.y, accA0_##e); \
    accA0_##e = fmaf(x0lo_##XS.z, a0.z, accA0_##e); \
    accA0_##e = fmaf(x0lo_##XS.w, a0.w, accA0_##e); \
    accA0_##e = fmaf(x0hi_##XS.x, a1.x, accA0_##e); \
    accA0_##e = fmaf(x0hi_##XS.y, a1.y, accA0_##e); \
    accA0_##e = fmaf(x0hi_##XS.z, a1.z, accA0_##e); \
    accA0_##e = fmaf(x0hi_##XS.w, a1.w, accA0_##e); \
    accA1_##e = fmaf(x1lo_##XS.x, a0.x, accA1_##e); \
    accA1_##e = fmaf(x1lo_##XS.y, a0.y, accA1_##e); \
    accA1_##e = fmaf(x1lo_##XS.z, a0.z, accA1_##e); \
    accA1_##e = fmaf(x1lo_##XS.w, a0.w, accA1_##e); \
    accA1_##e = fmaf(x1hi_##XS.x, a1.x, accA1_##e); \
    accA1_##e = fmaf(x1hi_##XS.y, a1.y, accA1_##e); \
    accA1_##e = fmaf(x1hi_##XS.z, a1.z, accA1_##e); \
    accA1_##e = fmaf(x1hi_##XS.w, a1.w, accA1_##e); \
    accB0_##e = fmaf(x0lo_##XS.x, b0.x, accB0_##e); \
    accB0_##e = fmaf(x0lo_##XS.y, b0.y, accB0_##e); \
    accB0_##e = fmaf(x0lo_##XS.z, b0.z, accB0_##e); \
    accB0_##e = fmaf(x0lo_##XS.w, b0.w, accB0_##e); \
    accB0_##e = fmaf(x0hi_##XS.x, b1.x, accB0_##e); \
    accB0_##e = fmaf(x0hi_##XS.y, b1.y, accB0_##e); \
    accB0_##e = fmaf(x0hi_##XS.z, b1.z, accB0_##e); \
    accB0_##e = fmaf(x0hi_##XS.w, b1.w, accB0_##e); \
    accB1_##e = fmaf(x1lo_##XS.x, b0.x, accB1_##e); \
    accB1_##e = fmaf(x1lo_##XS.y, b0.y, accB1_##e); \
    accB1_##e = fmaf(x1lo_##XS.z, b0.z, accB1_##e); \
    accB1_##e = fmaf(x1lo_##XS.w, b0.w, accB1_##e); \
    accB1_##e = fmaf(x1hi_##XS.x, b1.x, accB1_##e); \
    accB1_##e = fmaf(x1hi_##XS.y, b1.y, accB1_##e); \
    accB1_##e = fmaf(x1hi_##XS.z, b1.z, accB1_##e); \
    accB1_##e = fmaf(x1hi_##XS.w, b1.w, accB1_##e); }

#define COMPUTE(WT, XS) FOR_E2(FMA_ONE, WT, XS)

#define XLOAD(XS, S) \
    x0lo_##XS = *(const float4*)(xb0 + (S) * TKG);     \
    x0hi_##XS = *(const float4*)(xb0 + (S) * TKG + 4); \
    x1lo_##XS = *(const float4*)(xb1 + (S) * TKG);     \
    x1hi_##XS = *(const float4*)(xb1 + (S) * TKG + 4);

#define STAGE(DST, S) \
    { gload_lds16(wsrcA + (S) * TKG, (DST) + sdst0);   \
      gload_lds16(wsrcB + (S) * TKG, (DST) + sdst1); }

#define RED_ONE(e) \
    accA0_##e += __shfl_xor(accA0_##e, 1); accA0_##e += __shfl_xor(accA0_##e, 2); accA0_##e += __shfl_xor(accA0_##e, 4); \
    accA1_##e += __shfl_xor(accA1_##e, 1); accA1_##e += __shfl_xor(accA1_##e, 2); accA1_##e += __shfl_xor(accA1_##e, 4); \
    accB0_##e += __shfl_xor(accB0_##e, 1); accB0_##e += __shfl_xor(accB0_##e, 2); accB0_##e += __shfl_xor(accB0_##e, 4); \
    accB1_##e += __shfl_xor(accB1_##e, 1); accB1_##e += __shfl_xor(accB1_##e, 2); accB1_##e += __shfl_xor(accB1_##e, 4);

#define STORE_ONE(e) \
    dst0[e] = accA0_##e; dst0[16 + e] = accB0_##e; \
    dst1[e] = accA1_##e; dst1[16 + e] = accB1_##e;

__global__ __launch_bounds__(512)
void noisy_router_kernel(const float* __restrict__ x,
                         const float* __restrict__ noise,
                         const float* __restrict__ Wfc,
                         const float* __restrict__ bfc,
                         const float* __restrict__ Wns,
                         const float* __restrict__ bns,
                         float* __restrict__ out)
{
    __shared__ float lds[8192];    // 32 KB: wt[2 groups][2 bufs][32*64]; epilogue reuse

    const int tid  = threadIdx.x;
    const int lane = tid & 63;
    const int w    = tid >> 6;     // 0..7
    const int g    = w >> 2;       // K-group 0..1
    const int q    = w & 3;        // row-quarter 0..3
    const int seg  = lane & 7;
    const int rgrp = lane >> 3;

    const int rowbase = blockIdx.x * ROWS_PER_BLK + q * 16 + rgrp * 2;
    const int kbase   = g * KQ;
    const int wpo     = seg * 8;

    float* const wt0 = lds + (g * 2 + 0) * 2048;
    float* const wt1 = lds + (g * 2 + 1) * 2048;

    // staging map (proven v11): vt=0..255 per group; LDS rows 0..15 = Wfc,
    // 16..31 = Wns; byte addr = base + lane*16 (required gload_lds form).
    const int vt    = q * 64 + lane;
    const int wrow0 = vt >> 4;
    const int scol  = (vt & 15) * 4;
    const float* wsrcA = Wfc + (size_t)wrow0 * KD + kbase + scol;
    const float* wsrcB = Wns + (size_t)wrow0 * KD + kbase + scol;
    const int sdst0 = wrow0 * 64 + scol;
    const int sdst1 = (wrow0 + 16) * 64 + scol;

    const float* xb0 = x + (size_t)rowbase * KD + kbase + seg * 8;
    const float* xb1 = xb0 + KD;

    FOR_E1(DECL_ACC)                              // 64 named scalar accumulators
    float4 x0lo_A, x0hi_A, x1lo_A, x1hi_A;        // named x buffers
    float4 x0lo_B, x0hi_B, x1lo_B, x1hi_B;

    // prologue
    STAGE(wt0, 0);
    XLOAD(A, 0);

    #pragma unroll 1
    for (int sp = 0; sp < NSTEP; sp += 2) {
        __syncthreads();                 // tile sp + x(sp) ready (vmcnt drained)
        STAGE(wt1, sp + 1);
        XLOAD(B, sp + 1);
        COMPUTE(wt0, A);
        __syncthreads();                 // tile sp+1 ready
        if (sp + 2 < NSTEP) {
            STAGE(wt0, sp + 2);
            XLOAD(A, sp + 2);
        }
        COMPUTE(wt1, B);
    }

    // ---- butterfly over the 8 k-segs (masks 1,2,4 stay within seg-group) ----
    FOR_E1(RED_ONE)

    __syncthreads();                  // all tile reads done; lds reusable
    float* const slab = lds;          // [2 groups][64 rows][32 outs] = 4096 floats
    float* const red  = lds + 4096;   // [64 rows][stride 36]

    if (seg == 0) {
        float* dst0 = slab + g * 2048 + (q * 16 + rgrp * 2) * 32;
        float* dst1 = dst0 + 32;
        FOR_E1(STORE_ONE)
    }
    __syncthreads();

    {   // combine the 2 group-partials (float4 on LDS pointers only)
        const int row = tid >> 3, qd = tid & 7;
        float4 sum = make_float4(0.f, 0.f, 0.f, 0.f);
        const float4 v0 = *(const float4*)(slab + row * 32 + qd * 4);
        const float4 v1 = *(const float4*)(slab + 2048 + row * 32 + qd * 4);
        sum.x = v0.x + v1.x; sum.y = v0.y + v1.y;
        sum.z = v0.z + v1.z; sum.w = v0.w + v1.w;
        *(float4*)(red + row * 36 + qd * 4) = sum;
    }
    __syncthreads();

    // ---- per-row epilogue: softplus noise, top-2, sparse softmax ----
    if (tid < ROWS_PER_BLK) {
        const int r = tid;
        const float* rowp = red + r * 36;   // read LDS directly, no private copy
        const size_t grow = (size_t)blockIdx.x * ROWS_PER_BLK + r;
        const float* nzp = noise + grow * NE;

        float m1 = -1e30f, m2 = -1e30f;
        int i1 = 0, i2 = 0;
        #pragma unroll
        for (int j = 0; j < NE; ++j) {
            const float z  = rowp[16 + j] + bns[j];
            const float sp = fmaxf(z, 0.f) + log1pf(expf(-fabsf(z)));  // jax softplus
            const float v  = fmaf(nzp[j], sp, rowp[j] + bfc[j]);
            if (v > m1)      { m2 = m1; i2 = i1; m1 = v; i1 = j; }     // ties -> lower idx
            else if (v > m2) { m2 = v;  i2 = j; }
        }
        const float e2  = expf(m2 - m1);
        const float inv = 1.f / (1.f + e2);

        float* po = out + grow * NE;
        #pragma unroll
        for (int j = 0; j < NE; ++j) {
            po[j] = (j == i1) ? inv : ((j == i2) ? e2 * inv : 0.f);
        }
        float* pi = out + (size_t)NROWS * NE + grow * 2;
        pi[0] = (float)i1;
        pi[1] = (float)i2;
    }
}

extern "C" void kernel_launch(void* const* d_in, const int* in_sizes, int n_in,
                              void* d_out, int out_size, void* d_ws, size_t ws_size,
                              hipStream_t stream)
{
    const float* x     = (const float*)d_in[0];
    const float* noise = (const float*)d_in[1];
    const float* Wfc   = (const float*)d_in[2];
    const float* bfc   = (const float*)d_in[3];
    const float* Wns   = (const float*)d_in[4];
    const float* bns   = (const float*)d_in[5];
    float* out = (float*)d_out;

    noisy_router_kernel<<<NROWS / ROWS_PER_BLK, 512, 0, stream>>>(
        x, noise, Wfc, bfc, Wns, bns, out);
}

// Round 16
// 197.620 us; speedup vs baseline: 1.2662x; 1.2295x over previous
//
#include <hip/hip_runtime.h>
#include <hip/hip_bf16.h>

#define NROWS 16384   // B*S
#define KD    2048    // D
#define NE    16      // experts
#define ROWS_PER_BLK 64
#define NG    4              // K-groups
#define KQ    (KD / NG)      // 512
#define TKG   64             // K-floats staged per group per step
#define NSTEP (KQ / TKG)     // 8

// v15: R=4 rows/lane, 4-way K-split, VGPR budget raised via amdgpu_waves_per_eu(2).
// Diagnosis of rounds 8-14: backend pinned VGPR alloc at 128 (4 waves/EU target)
// while demand was ~150-200 -> allocator spilled the accumulators once per step
// (64 acc x 4B x 131072 thr x 16 steps = 537 MB = observed WRITE_SIZE). Named
// scalars / launch_bounds didn't move it; waves_per_eu(2) -> budget 256 should.
//  - block = 512 thr / 8 waves; wave w -> (K-group g=w>>1, row-half h=w&1)
//  - lane = (rgrp=lane>>3 -> 4 rows, seg=lane&7 -> 8-float K-slice per step)
//  - W-stack tile [32][64] per group, double-buffered, via global_load_lds
//  - x single-buffered in regs, loaded BEFORE stage issue (x-wait = vmcnt(8))
//  - FMA:ds_read = 16:1
// Output FLOAT32: [262144 probs][32768 ids-as-floats].

__device__ __forceinline__ void gload_lds16(const float* g, float* l) {
    __builtin_amdgcn_global_load_lds(
        (const __attribute__((address_space(1))) void*)g,
        (__attribute__((address_space(3))) void*)l,
        16, 0, 0);
}

__global__ __launch_bounds__(512)
__attribute__((amdgpu_waves_per_eu(2)))
void noisy_router_kernel(const float* __restrict__ x,
                         const float* __restrict__ noise,
                         const float* __restrict__ Wfc,
                         const float* __restrict__ bfc,
                         const float* __restrict__ Wns,
                         const float* __restrict__ bns,
                         float* __restrict__ out)
{
    __shared__ float lds[16384];   // 64 KB: wt[4 groups][2 bufs][32*64]; epilogue reuse

    const int tid  = threadIdx.x;
    const int lane = tid & 63;
    const int w    = tid >> 6;     // 0..7
    const int g    = w >> 1;       // K-group 0..3
    const int h    = w & 1;        // row-half 0..1
    const int seg  = lane & 7;
    const int rgrp = lane >> 3;

    const int rowbase = blockIdx.x * ROWS_PER_BLK + h * 32 + rgrp * 4;
    const int kbase   = g * KQ;

    float* const wt0 = lds + (g * 2 + 0) * 2048;
    float* const wt1 = lds + (g * 2 + 1) * 2048;

    // staging: group g's 2 waves (h=0,1) fill [32][64]; wave-instr i covers 8
    // LDS rows; dest byte = base(i,h) + lane*16 (required linear form).
    // LDS rows 0..15 = Wfc experts, 16..31 = Wns experts.
    const int r0   = h * 4 + (lane >> 4);        // 0..7
    const int scol = (lane & 15) * 4;
    const float* wsF = Wfc + (size_t)r0 * KD + kbase + scol;
    const float* wsN = Wns + (size_t)r0 * KD + kbase + scol;
    const int sd = r0 * 64 + scol;               // +512 floats per instr block

    const float* xb = x + (size_t)rowbase * KD + kbase + seg * 8;

    float accA[4][NE], accB[4][NE];
    #pragma unroll
    for (int j = 0; j < 4; ++j)
        #pragma unroll
        for (int e = 0; e < NE; ++e) { accA[j][e] = 0.f; accB[j][e] = 0.f; }

    float4 xv[4][2];   // single x buffer; indices static under full unroll

#define STAGE(DST, S) { \
    gload_lds16(wsF +          (S) * TKG, (DST) + sd);        \
    gload_lds16(wsF + 8 * KD + (S) * TKG, (DST) + sd + 512);  \
    gload_lds16(wsN +          (S) * TKG, (DST) + sd + 1024); \
    gload_lds16(wsN + 8 * KD + (S) * TKG, (DST) + sd + 1536); }

#define XLOAD(S) { _Pragma("unroll") \
    for (int j = 0; j < 4; ++j) { \
        xv[j][0] = *(const float4*)(xb + (size_t)j * KD + (S) * TKG);     \
        xv[j][1] = *(const float4*)(xb + (size_t)j * KD + (S) * TKG + 4); } }

#define COMPUTE(WT) { const float* wp = (WT) + seg * 8; \
    _Pragma("unroll") \
    for (int e = 0; e < NE; ++e) { \
        const float4 a0 = *(const float4*)(wp + e * 64);              \
        const float4 a1 = *(const float4*)(wp + e * 64 + 4);          \
        const float4 b0 = *(const float4*)(wp + (16 + e) * 64);       \
        const float4 b1 = *(const float4*)(wp + (16 + e) * 64 + 4);   \
        _Pragma("unroll") \
        for (int j = 0; j < 4; ++j) { \
            const float4 x0 = xv[j][0], x1 = xv[j][1]; \
            float sA = accA[j][e], sB = accB[j][e]; \
            sA = fmaf(x0.x, a0.x, sA); sA = fmaf(x0.y, a0.y, sA); \
            sA = fmaf(x0.z, a0.z, sA); sA = fmaf(x0.w, a0.w, sA); \
            sA = fmaf(x1.x, a1.x, sA); sA = fmaf(x1.y, a1.y, sA); \
            sA = fmaf(x1.z, a1.z, sA); sA = fmaf(x1.w, a1.w, sA); \
            sB = fmaf(x0.x, b0.x, sB); sB = fmaf(x0.y, b0.y, sB); \
            sB = fmaf(x0.z, b0.z, sB); sB = fmaf(x0.w, b0.w, sB); \
            sB = fmaf(x1.x, b1.x, sB); sB = fmaf(x1.y, b1.y, sB); \
            sB = fmaf(x1.z, b1.z, sB); sB = fmaf(x1.w, b1.w, sB); \
            accA[j][e] = sA; accB[j][e] = sB; \
        } } }

    // prologue
    STAGE(wt0, 0);

    #pragma unroll 1
    for (int sp = 0; sp < NSTEP; sp += 2) {
        __syncthreads();                 // tile sp staged (vmcnt drained)
        XLOAD(sp);                       // x first: its wait leaves stages in flight
        STAGE(wt1, sp + 1);
        COMPUTE(wt0);
        __syncthreads();                 // tile sp+1 staged
        XLOAD(sp + 1);
        if (sp + 2 < NSTEP) STAGE(wt0, sp + 2);
        COMPUTE(wt1);
    }
#undef STAGE
#undef XLOAD
#undef COMPUTE

    // ---- butterfly over the 8 k-segs (masks 1,2,4 stay within seg-group) ----
    #pragma unroll
    for (int j = 0; j < 4; ++j)
        #pragma unroll
        for (int e = 0; e < NE; ++e) {
            float a = accA[j][e], b = accB[j][e];
            a += __shfl_xor(a, 1); a += __shfl_xor(a, 2); a += __shfl_xor(a, 4);
            b += __shfl_xor(b, 1); b += __shfl_xor(b, 2); b += __shfl_xor(b, 4);
            accA[j][e] = a; accB[j][e] = b;
        }

    __syncthreads();                  // all tile reads done; lds reusable
    float* const slab = lds;          // [4 groups][64 rows][32 outs] = 8192 floats
    float* const red  = lds + 8192;   // [64 rows][stride 36]

    if (seg == 0) {
        #pragma unroll
        for (int j = 0; j < 4; ++j) {
            float* dst = slab + g * 2048 + (h * 32 + rgrp * 4 + j) * 32;
            #pragma unroll
            for (int e = 0; e < NE; ++e) { dst[e] = accA[j][e]; dst[16 + e] = accB[j][e]; }
        }
    }
    __syncthreads();

    {   // combine the 4 group-partials (float4 on LDS pointers only)
        const int row = tid >> 3, qd = tid & 7;
        float4 sum = make_float4(0.f, 0.f, 0.f, 0.f);
        #pragma unroll
        for (int gg = 0; gg < NG; ++gg) {
            const float4 v = *(const float4*)(slab + gg * 2048 + row * 32 + qd * 4);
            sum.x += v.x; sum.y += v.y; sum.z += v.z; sum.w += v.w;
        }
        *(float4*)(red + row * 36 + qd * 4) = sum;
    }
    __syncthreads();

    // ---- per-row epilogue: softplus noise, top-2, sparse softmax ----
    if (tid < ROWS_PER_BLK) {
        const int r = tid;
        const float* rowp = red + r * 36;
        const size_t grow = (size_t)blockIdx.x * ROWS_PER_BLK + r;
        const float* nzp = noise + grow * NE;

        float m1 = -1e30f, m2 = -1e30f;
        int i1 = 0, i2 = 0;
        #pragma unroll
        for (int j = 0; j < NE; ++j) {
            const float z  = rowp[16 + j] + bns[j];
            const float sp = fmaxf(z, 0.f) + log1pf(expf(-fabsf(z)));  // jax softplus
            const float v  = fmaf(nzp[j], sp, rowp[j] + bfc[j]);
            if (v > m1)      { m2 = m1; i2 = i1; m1 = v; i1 = j; }     // ties -> lower idx
            else if (v > m2) { m2 = v;  i2 = j; }
        }
        const float e2  = expf(m2 - m1);
        const float inv = 1.f / (1.f + e2);

        float* po = out + grow * NE;
        #pragma unroll
        for (int j = 0; j < NE; ++j) {
            po[j] = (j == i1) ? inv : ((j == i2) ? e2 * inv : 0.f);
        }
        float* pi = out + (size_t)NROWS * NE + grow * 2;
        pi[0] = (float)i1;
        pi[1] = (float)i2;
    }
}

extern "C" void kernel_launch(void* const* d_in, const int* in_sizes, int n_in,
                              void* d_out, int out_size, void* d_ws, size_t ws_size,
                              hipStream_t stream)
{
    const float* x     = (const float*)d_in[0];
    const float* noise = (const float*)d_in[1];
    const float* Wfc   = (const float*)d_in[2];
    const float* bfc   = (const float*)d_in[3];
    const float* Wns   = (const float*)d_in[4];
    const float* bns   = (const float*)d_in[5];
    float* out = (float*)d_out;

    noisy_router_kernel<<<NROWS / ROWS_PER_BLK, 512, 0, stream>>>(
        x, noise, Wfc, bfc, Wns, bns, out);
}

// Round 17
// 56.907 us; speedup vs baseline: 4.3970x; 3.4727x over previous
//
#include <hip/hip_runtime.h>
#include <hip/hip_bf16.h>

#define NROWS 16384   // B*S
#define KD    2048    // D
#define NE    16      // experts
#define ROWS_PER_BLK 64
#define NT    32      // K tiles of 64 floats (full K per wave, no K-split)

// v17: expert-split (no K-split), R=4 rows/lane, sized for the immovable
// 128-VGPR budget (rounds 8-16: every geometry with >32 acc floats spilled
// ~N_acc*4B*131072thr*NSTEP bytes of scratch; v7 at 32 acc floats was clean).
//  - block = 512 thr / 8 waves; wave w -> (expert-quartet eq=w&3, row-half rh=w>>2)
//  - lane = (rgrp=lane>>3 -> 4 rows, seg=lane&7 -> 8-float K-slice per tile)
//  - acc = 4 rows x 4 experts x 2 mats = 32 floats; FMA:ds_read = 16:1
//  - W tile [32 rows][64] dbuf in LDS (16 KB), 1 global_load_lds per thread
//  - x loads issued BEFORE next STAGE -> x-wait = vmcnt(1), stage stays in flight
//  - epilogue: seg-butterfly -> slab[64][33] -> per-row softplus/top2/softmax
// Output FLOAT32: [262144 probs][32768 ids-as-floats].

__device__ __forceinline__ void gload_lds16(const float* g, float* l) {
    __builtin_amdgcn_global_load_lds(
        (const __attribute__((address_space(1))) void*)g,
        (__attribute__((address_space(3))) void*)l,
        16, 0, 0);
}

__global__ __launch_bounds__(512)
void noisy_router_kernel(const float* __restrict__ x,
                         const float* __restrict__ noise,
                         const float* __restrict__ Wfc,
                         const float* __restrict__ bfc,
                         const float* __restrict__ Wns,
                         const float* __restrict__ bns,
                         float* __restrict__ out)
{
    __shared__ float lds[4096];    // 16 KB: wt0[32*64] + wt1[32*64]; slab reuse

    const int tid  = threadIdx.x;
    const int lane = tid & 63;
    const int w    = tid >> 6;     // 0..7
    const int eq   = w & 3;        // expert quartet 0..3
    const int rh   = w >> 2;       // row half 0..1
    const int seg  = lane & 7;
    const int rgrp = lane >> 3;

    const int rowbase = blockIdx.x * ROWS_PER_BLK + rh * 32 + rgrp * 4;

    float* const wt0 = lds;
    float* const wt1 = lds + 2048;

    // staging: LDS row = w*4 + (lane>>4) (rows 0..15 = Wfc, 16..31 = Wns),
    // col = (lane&15)*4 -> dest byte = w*1024 + lane*16 (required linear form).
    const int srow = w * 4 + (lane >> 4);
    const float* wsrc = (srow < 16 ? Wfc + (size_t)srow * KD
                                   : Wns + (size_t)(srow - 16) * KD) + (lane & 15) * 4;
    const int sdst = srow * 64 + (lane & 15) * 4;

    const float* xb = x + (size_t)rowbase * KD + seg * 8;

    float accA[4][4], accB[4][4];          // [row j][expert e] -- 32 floats
    #pragma unroll
    for (int j = 0; j < 4; ++j)
        #pragma unroll
        for (int e = 0; e < 4; ++e) { accA[j][e] = 0.f; accB[j][e] = 0.f; }

#define STAGE(DST, T) gload_lds16(wsrc + (T) * 64, (DST) + sdst);

#define BODY(WT, T) { \
    float4 xv0_0, xv0_1, xv1_0, xv1_1, xv2_0, xv2_1, xv3_0, xv3_1;      \
    xv0_0 = *(const float4*)(xb + 0 * KD + (T) * 64);                   \
    xv0_1 = *(const float4*)(xb + 0 * KD + (T) * 64 + 4);               \
    xv1_0 = *(const float4*)(xb + 1 * KD + (T) * 64);                   \
    xv1_1 = *(const float4*)(xb + 1 * KD + (T) * 64 + 4);               \
    xv2_0 = *(const float4*)(xb + 2 * KD + (T) * 64);                   \
    xv2_1 = *(const float4*)(xb + 2 * KD + (T) * 64 + 4);               \
    xv3_0 = *(const float4*)(xb + 3 * KD + (T) * 64);                   \
    xv3_1 = *(const float4*)(xb + 3 * KD + (T) * 64 + 4);               \
    if ((T) + 1 < NT) { STAGE(((T) & 1) ? wt0 : wt1, (T) + 1) }         \
    const float* wpA = (WT) + eq * 256 + seg * 8;                       \
    const float* wpB = wpA + 1024;                                      \
    _Pragma("unroll")                                                   \
    for (int e = 0; e < 4; ++e) {                                       \
        const float4 a0 = *(const float4*)(wpA + e * 64);               \
        const float4 a1 = *(const float4*)(wpA + e * 64 + 4);           \
        const float4 b0 = *(const float4*)(wpB + e * 64);               \
        const float4 b1 = *(const float4*)(wpB + e * 64 + 4);           \
        accA[0][e] = fmaf(xv0_0.x, a0.x, accA[0][e]);                   \
        accA[0][e] = fmaf(xv0_0.y, a0.y, accA[0][e]);                   \
        accA[0][e] = fmaf(xv0_0.z, a0.z, accA[0][e]);                   \
        accA[0][e] = fmaf(xv0_0.w, a0.w, accA[0][e]);                   \
        accA[0][e] = fmaf(xv0_1.x, a1.x, accA[0][e]);                   \
        accA[0][e] = fmaf(xv0_1.y, a1.y, accA[0][e]);                   \
        accA[0][e] = fmaf(xv0_1.z, a1.z, accA[0][e]);                   \
        accA[0][e] = fmaf(xv0_1.w, a1.w, accA[0][e]);                   \
        accB[0][e] = fmaf(xv0_0.x, b0.x, accB[0][e]);                   \
        accB[0][e] = fmaf(xv0_0.y, b0.y, accB[0][e]);                   \
        accB[0][e] = fmaf(xv0_0.z, b0.z, accB[0][e]);                   \
        accB[0][e] = fmaf(xv0_0.w, b0.w, accB[0][e]);                   \
        accB[0][e] = fmaf(xv0_1.x, b1.x, accB[0][e]);                   \
        accB[0][e] = fmaf(xv0_1.y, b1.y, accB[0][e]);                   \
        accB[0][e] = fmaf(xv0_1.z, b1.z, accB[0][e]);                   \
        accB[0][e] = fmaf(xv0_1.w, b1.w, accB[0][e]);                   \
        accA[1][e] = fmaf(xv1_0.x, a0.x, accA[1][e]);                   \
        accA[1][e] = fmaf(xv1_0.y, a0.y, accA[1][e]);                   \
        accA[1][e] = fmaf(xv1_0.z, a0.z, accA[1][e]);                   \
        accA[1][e] = fmaf(xv1_0.w, a0.w, accA[1][e]);                   \
        accA[1][e] = fmaf(xv1_1.x, a1.x, accA[1][e]);                   \
        accA[1][e] = fmaf(xv1_1.y, a1.y, accA[1][e]);                   \
        accA[1][e] = fmaf(xv1_1.z, a1.z, accA[1][e]);                   \
        accA[1][e] = fmaf(xv1_1.w, a1.w, accA[1][e]);                   \
        accB[1][e] = fmaf(xv1_0.x, b0.x, accB[1][e]);                   \
        accB[1][e] = fmaf(xv1_0.y, b0.y, accB[1][e]);                   \
        accB[1][e] = fmaf(xv1_0.z, b0.z, accB[1][e]);                   \
        accB[1][e] = fmaf(xv1_0.w, b0.w, accB[1][e]);                   \
        accB[1][e] = fmaf(xv1_1.x, b1.x, accB[1][e]);                   \
        accB[1][e] = fmaf(xv1_1.y, b1.y, accB[1][e]);                   \
        accB[1][e] = fmaf(xv1_1.z, b1.z, accB[1][e]);                   \
        accB[1][e] = fmaf(xv1_1.w, b1.w, accB[1][e]);                   \
        accA[2][e] = fmaf(xv2_0.x, a0.x, accA[2][e]);                   \
        accA[2][e] = fmaf(xv2_0.y, a0.y, accA[2][e]);                   \
        accA[2][e] = fmaf(xv2_0.z, a0.z, accA[2][e]);                   \
        accA[2][e] = fmaf(xv2_0.w, a0.w, accA[2][e]);                   \
        accA[2][e] = fmaf(xv2_1.x, a1.x, accA[2][e]);                   \
        accA[2][e] = fmaf(xv2_1.y, a1.y, accA[2][e]);                   \
        accA[2][e] = fmaf(xv2_1.z, a1.z, accA[2][e]);                   \
        accA[2][e] = fmaf(xv2_1.w, a1.w, accA[2][e]);                   \
        accB[2][e] = fmaf(xv2_0.x, b0.x, accB[2][e]);                   \
        accB[2][e] = fmaf(xv2_0.y, b0.y, accB[2][e]);                   \
        accB[2][e] = fmaf(xv2_0.z, b0.z, accB[2][e]);                   \
        accB[2][e] = fmaf(xv2_0.w, b0.w, accB[2][e]);                   \
        accB[2][e] = fmaf(xv2_1.x, b1.x, accB[2][e]);                   \
        accB[2][e] = fmaf(xv2_1.y, b1.y, accB[2][e]);                   \
        accB[2][e] = fmaf(xv2_1.z, b1.z, accB[2][e]);                   \
        accB[2][e] = fmaf(xv2_1.w, b1.w, accB[2][e]);                   \
        accA[3][e] = fmaf(xv3_0.x, a0.x, accA[3][e]);                   \
        accA[3][e] = fmaf(xv3_0.y, a0.y, accA[3][e]);                   \
        accA[3][e] = fmaf(xv3_0.z, a0.z, accA[3][e]);                   \
        accA[3][e] = fmaf(xv3_0.w, a0.w, accA[3][e]);                   \
        accA[3][e] = fmaf(xv3_1.x, a1.x, accA[3][e]);                   \
        accA[3][e] = fmaf(xv3_1.y, a1.y, accA[3][e]);                   \
        accA[3][e] = fmaf(xv3_1.z, a1.z, accA[3][e]);                   \
        accA[3][e] = fmaf(xv3_1.w, a1.w, accA[3][e]);                   \
        accB[3][e] = fmaf(xv3_0.x, b0.x, accB[3][e]);                   \
        accB[3][e] = fmaf(xv3_0.y, b0.y, accB[3][e]);                   \
        accB[3][e] = fmaf(xv3_0.z, b0.z, accB[3][e]);                   \
        accB[3][e] = fmaf(xv3_0.w, b0.w, accB[3][e]);                   \
        accB[3][e] = fmaf(xv3_1.x, b1.x, accB[3][e]);                   \
        accB[3][e] = fmaf(xv3_1.y, b1.y, accB[3][e]);                   \
        accB[3][e] = fmaf(xv3_1.z, b1.z, accB[3][e]);                   \
        accB[3][e] = fmaf(xv3_1.w, b1.w, accB[3][e]);                   \
    } }

    // prologue
    STAGE(wt0, 0)

    #pragma unroll 1
    for (int tp = 0; tp < NT; tp += 2) {
        __syncthreads();               // stage(tp) done (vmcnt drained at barrier)
        BODY(wt0, tp)                  // x-loads first, stage(tp+1) inside, FMAs
        __syncthreads();               // stage(tp+1) done
        BODY(wt1, tp + 1)
    }
#undef STAGE
#undef BODY

    // ---- butterfly over the 8 k-segs (masks 1,2,4 stay within seg-group) ----
    #pragma unroll
    for (int j = 0; j < 4; ++j)
        #pragma unroll
        for (int e = 0; e < 4; ++e) {
            float a = accA[j][e], b = accB[j][e];
            a += __shfl_xor(a, 1); a += __shfl_xor(a, 2); a += __shfl_xor(a, 4);
            b += __shfl_xor(b, 1); b += __shfl_xor(b, 2); b += __shfl_xor(b, 4);
            accA[j][e] = a; accB[j][e] = b;
        }

    __syncthreads();                  // all tile reads done; lds reusable as slab
    float* const slab = lds;          // [64 rows][stride 33]

    if (seg == 0) {                   // each wave owns complete (row, e-quartet) outs
        #pragma unroll
        for (int j = 0; j < 4; ++j) {
            float* dst = slab + (rh * 32 + rgrp * 4 + j) * 33 + eq * 4;
            #pragma unroll
            for (int e = 0; e < 4; ++e) { dst[e] = accA[j][e]; dst[16 + e] = accB[j][e]; }
        }
    }
    __syncthreads();

    // ---- per-row epilogue: softplus noise, top-2, sparse softmax ----
    if (tid < ROWS_PER_BLK) {
        const int r = tid;
        const float* rowp = slab + r * 33;
        const size_t grow = (size_t)blockIdx.x * ROWS_PER_BLK + r;
        const float* nzp = noise + grow * NE;

        float m1 = -1e30f, m2 = -1e30f;
        int i1 = 0, i2 = 0;
        #pragma unroll
        for (int j = 0; j < NE; ++j) {
            const float z  = rowp[16 + j] + bns[j];
            const float sp = fmaxf(z, 0.f) + log1pf(expf(-fabsf(z)));  // jax softplus
            const float v  = fmaf(nzp[j], sp, rowp[j] + bfc[j]);
            if (v > m1)      { m2 = m1; i2 = i1; m1 = v; i1 = j; }     // ties -> lower idx
            else if (v > m2) { m2 = v;  i2 = j; }
        }
        const float e2  = expf(m2 - m1);
        const float inv = 1.f / (1.f + e2);

        float* po = out + grow * NE;
        #pragma unroll
        for (int j = 0; j < NE; ++j) {
            po[j] = (j == i1) ? inv : ((j == i2) ? e2 * inv : 0.f);
        }
        float* pi = out + (size_t)NROWS * NE + grow * 2;
        pi[0] = (float)i1;
        pi[1] = (float)i2;
    }
}

extern "C" void kernel_launch(void* const* d_in, const int* in_sizes, int n_in,
                              void* d_out, int out_size, void* d_ws, size_t ws_size,
                              hipStream_t stream)
{
    const float* x     = (const float*)d_in[0];
    const float* noise = (const float*)d_in[1];
    const float* Wfc   = (const float*)d_in[2];
    const float* bfc   = (const float*)d_in[3];
    const float* Wns   = (const float*)d_in[4];
    const float* bns   = (const float*)d_in[5];
    float* out = (float*)d_out;

    noisy_router_kernel<<<NROWS / ROWS_PER_BLK, 512, 0, stream>>>(
        x, noise, Wfc, bfc, Wns, bns, out);
}